// Round 2
// baseline (2187.555 us; speedup 1.0000x reference)
//
#include <hip/hip_runtime.h>

#define NPIX 16384   // 16*32*32
#define DIM  256
#define NEMB 8192

// ---------------- K0: codebook squared norms (one wave per code) ----------------
__global__ __launch_bounds__(256) void k_cbnorm(const float* __restrict__ cb,
                                                float* __restrict__ cbn) {
  const int wid  = blockIdx.x * 4 + (threadIdx.x >> 6);   // code index 0..8191
  const int lane = threadIdx.x & 63;
  const float4 v = reinterpret_cast<const float4*>(cb)[wid * 64 + lane];
  float s = v.x * v.x + v.y * v.y + v.z * v.z + v.w * v.w;
#pragma unroll
  for (int m = 32; m >= 1; m >>= 1) s += __shfl_xor(s, m, 64);
  if (lane == 0) cbn[wid] = s;
}

// ---------------- K1: transpose x [b][c][hw] -> xt [pix][c] ----------------
__global__ __launch_bounds__(256) void k_xpose(const float* __restrict__ x,
                                               float* __restrict__ xt) {
  __shared__ float tile[64][36];
  const int t = threadIdx.x, blk = blockIdx.x;
  const int b = blk >> 4, hw0 = (blk & 15) << 6;
  const size_t xbase = ((size_t)b << 18) + hw0;
  const int hwL = t & 63, cr = t >> 6;     // read mapping
  const int pixL = t >> 2, c4 = t & 3;     // write mapping
  for (int ch = 0; ch < 8; ++ch) {
    __syncthreads();
#pragma unroll
    for (int i = 0; i < 8; ++i) {
      const int cloc = cr + 4 * i;         // 0..31
      tile[hwL][cloc] = x[xbase + ((size_t)(ch * 32 + cloc) << 10) + hwL];
    }
    __syncthreads();
    const size_t row = (size_t)(b * 1024 + hw0 + pixL) * 256 + ch * 32 + c4 * 8;
#pragma unroll
    for (int u = 0; u < 2; ++u)
      *reinterpret_cast<float4*>(&xt[row + u * 4]) =
          *reinterpret_cast<const float4*>(&tile[pixL][c4 * 8 + u * 4]);
  }
}

// ---------------- K1b: x row squared norms (one wave per pixel, from xt) ------
__global__ __launch_bounds__(256) void k_xnorm(const float* __restrict__ xt,
                                               float* __restrict__ xn) {
  const int wid  = blockIdx.x * 4 + (threadIdx.x >> 6);   // pixel 0..16383
  const int lane = threadIdx.x & 63;
  const float4 v = reinterpret_cast<const float4*>(xt)[(size_t)wid * 64 + lane];
  float s = fmaf(v.x, v.x, fmaf(v.y, v.y, fmaf(v.z, v.z, v.w * v.w)));
#pragma unroll
  for (int m = 32; m >= 1; m >>= 1) s += __shfl_xor(s, m, 64);
  if (lane == 0) xn[wid] = s;
}

// ---------------- K2: argmin over codes (fp32 VALU GEMM) ----------------
// 256 blocks x 512 threads. Block = 64 pixels x all 8192 codes.
// wave w handles pixels {w + 8i}; lane = code-group cg; codes k = ct*512 + cg + 64j.
// cb tile (512 codes x 8 c) LDS double-buffered; x fragments wave-uniform global loads.
// dist replicates np f32: R( R(cbn+xn) - 2*dot_f32 ), first-index tie-break.
__global__ __launch_bounds__(512, 2) void k_argmin(const float* __restrict__ xt,
                                                   const float* __restrict__ cb,
                                                   const float* __restrict__ cbn,
                                                   const float* __restrict__ xn,
                                                   int* __restrict__ ids) {
  __shared__ float csm[2][2][512][4];   // [buf][q-chunk][code row][4 c] = 32 KB
  const int t    = threadIdx.x;
  const int lane = t & 63;              // cg
  const int w    = t >> 6;              // wave id = pixel group
  const int p0   = blockIdx.x * 64;

  float xnr[8];
#pragma unroll
  for (int i = 0; i < 8; ++i) xnr[i] = xn[p0 + w + 8 * i];

  float bd[8];
  int   bk[8];
#pragma unroll
  for (int i = 0; i < 8; ++i) { bd[i] = 3.4e38f; bk[i] = 0; }

  float acc[8][8];

  // reg-staged prefetch: thread t owns code row t of each 512-row tile.
  auto loadregs = [&](float4& r0, float4& r1, int u) {  // u = stage id 0..511
    const int ct = u >> 5, cc = u & 31;
    const float* src = cb + ((size_t)(ct * 512 + t)) * 256 + cc * 8;
    r0 = *reinterpret_cast<const float4*>(src);
    r1 = *reinterpret_cast<const float4*>(src + 4);
  };
  auto writeregs = [&](const float4& r0, const float4& r1, int buf) {
    *reinterpret_cast<float4*>(&csm[buf][0][t][0]) = r0;
    *reinterpret_cast<float4*>(&csm[buf][1][t][0]) = r1;
  };

#define COMPUTE(BUF, U)                                                          \
  {                                                                              \
    const int ct = (U) >> 5, cc = (U) & 31;                                      \
    if (cc == 0) {                                                               \
      _Pragma("unroll") for (int i = 0; i < 8; ++i)                              \
          _Pragma("unroll") for (int j = 0; j < 8; ++j) acc[i][j] = 0.f;         \
    }                                                                            \
    _Pragma("unroll") for (int q = 0; q < 2; ++q) {                              \
      float4 xa[8], ca[8];                                                       \
      _Pragma("unroll") for (int i = 0; i < 8; ++i)                              \
          xa[i] = *reinterpret_cast<const float4*>(                              \
              &xt[(size_t)(p0 + w + 8 * i) * 256 + cc * 8 + q * 4]);             \
      _Pragma("unroll") for (int j = 0; j < 8; ++j)                              \
          ca[j] = *reinterpret_cast<const float4*>(&csm[BUF][q][lane + 64 * j][0]); \
      _Pragma("unroll") for (int i = 0; i < 8; ++i)                              \
          _Pragma("unroll") for (int j = 0; j < 8; ++j) {                        \
        acc[i][j] = fmaf(xa[i].x, ca[j].x, acc[i][j]);                           \
        acc[i][j] = fmaf(xa[i].y, ca[j].y, acc[i][j]);                           \
        acc[i][j] = fmaf(xa[i].z, ca[j].z, acc[i][j]);                           \
        acc[i][j] = fmaf(xa[i].w, ca[j].w, acc[i][j]);                           \
      }                                                                          \
    }                                                                            \
    if (cc == 31) {                                                              \
      _Pragma("unroll") for (int j = 0; j < 8; ++j) {                            \
        const int k = ct * 512 + lane + 64 * j;                                  \
        const float cn = cbn[k];                                                 \
        _Pragma("unroll") for (int i = 0; i < 8; ++i) {                          \
          const float sq = cn + xnr[i];          /* == xn exactly (cbn tiny) */  \
          const float d  = fmaf(-2.f, acc[i][j], sq);                            \
          if (d < bd[i]) { bd[i] = d; bk[i] = k; }                               \
        }                                                                        \
      }                                                                          \
    }                                                                            \
  }

  float4 rA0, rA1, rB0, rB1;
  // prologue: stage 0 -> buf0; stage 1 -> regs B
  loadregs(rA0, rA1, 0);
  writeregs(rA0, rA1, 0);
  loadregs(rB0, rB1, 1);
  __syncthreads();

#pragma unroll 1
  for (int m = 0; m < 256; ++m) {
    const int uA = 2 * m, uB = 2 * m + 1;
    // --- sub-stage A: compute buf0 (stage uA) ---
    writeregs(rB0, rB1, 1);                       // stage uA+1 -> buf1
    if (uA + 2 < 512) loadregs(rA0, rA1, uA + 2); // prefetch stage uA+2
    COMPUTE(0, uA);
    __syncthreads();
    // --- sub-stage B: compute buf1 (stage uB) ---
    if (uB + 1 < 512) writeregs(rA0, rA1, 0);     // stage uB+1 -> buf0
    if (uB + 2 < 512) loadregs(rB0, rB1, uB + 2); // prefetch stage uB+2
    COMPUTE(1, uB);
    __syncthreads();
  }
#undef COMPUTE

  // per-pixel lexicographic (d, k) min across the 64 lanes
#pragma unroll
  for (int i = 0; i < 8; ++i) {
    float d = bd[i];
    int   k = bk[i];
#pragma unroll
    for (int off = 32; off >= 1; off >>= 1) {
      const float d2 = __shfl_xor(d, off, 64);
      const int   k2 = __shfl_xor(k, off, 64);
      if (d2 < d || (d2 == d && k2 < k)) { d = d2; k = k2; }
    }
    if (lane == 0) ids[p0 + w + 8 * i] = k;
  }
}

// ---------------- K3: gather + emb_out + ids-as-float + loss partials ----------------
__global__ __launch_bounds__(256) void k_out(const float* __restrict__ x,
                                             const float* __restrict__ cb,
                                             const int* __restrict__ ids,
                                             float* __restrict__ out,
                                             double* __restrict__ partials) {
  __shared__ float  es[64 * 68];
  __shared__ double red[256];
  const int t = threadIdx.x, blk = blockIdx.x;
  const int n0 = blk * 64;
  const int b = blk >> 4, hw0 = (blk & 15) << 6;
  const size_t xbase = ((size_t)b << 18) + hw0;
  const int p = t >> 2, c4 = t & 3;        // staging
  const int lane = t & 63, cgr = t >> 6;   // compute
  double acc = 0.0;
  float* out_emb = out + NPIX;
  for (int cc = 0; cc < 4; ++cc) {
    const int cbase = cc * 64;
    __syncthreads();
    const int id = ids[n0 + p];
#pragma unroll
    for (int i = 0; i < 4; ++i) {
      const int cl = c4 * 16 + i * 4;
      *reinterpret_cast<float4*>(&es[p * 68 + cl]) =
          *reinterpret_cast<const float4*>(&cb[(size_t)id * 256 + cbase + cl]);
    }
    __syncthreads();
#pragma unroll
    for (int i = 0; i < 16; ++i) {
      const int c = cgr * 16 + i;
      const size_t g = xbase + ((size_t)(cbase + c) << 10) + lane;
      const float xv = x[g];
      const float ev = es[lane * 68 + c];
      const float d = xv - ev;
      acc += (double)d * (double)d;
      out_emb[g] = xv + (ev - xv);   // replicate straight-through rounding exactly
    }
  }
  if (t < 64) out[n0 + t] = (float)ids[n0 + t];
  __syncthreads();
  red[t] = acc;
  __syncthreads();
  for (int sft = 128; sft >= 1; sft >>= 1) {
    if (t < sft) red[t] += red[t + sft];
    __syncthreads();
  }
  if (t == 0) partials[blk] = red[0];
}

// ---------------- K4: finalize loss ----------------
__global__ __launch_bounds__(256) void k_loss(const double* __restrict__ partials,
                                              float* __restrict__ out) {
  __shared__ double red[256];
  const int t = threadIdx.x;
  red[t] = partials[t];
  __syncthreads();
  for (int sft = 128; sft >= 1; sft >>= 1) {
    if (t < sft) red[t] += red[t + sft];
    __syncthreads();
  }
  if (t == 0) {
    const float m = (float)(red[0] / 4194304.0);     // mean((x-emb)^2)
    out[NPIX + (size_t)NPIX * 256] = m + 0.25f * m;  // dict + BETA*commitment
  }
}

extern "C" void kernel_launch(void* const* d_in, const int* in_sizes, int n_in,
                              void* d_out, int out_size, void* d_ws, size_t ws_size,
                              hipStream_t stream) {
  const float* x  = (const float*)d_in[0];   // [16,256,32,32]
  const float* cb = (const float*)d_in[1];   // [8192,256]
  float* out = (float*)d_out;                // [ids | emb_out | loss]

  char* wsb = (char*)d_ws;
  float*  cbn      = (float*)wsb;                         // 32 KB
  float*  xn       = (float*)(wsb + (32 << 10));          // 64 KB
  int*    ids      = (int*)(wsb + (96 << 10));            // 64 KB
  double* partials = (double*)(wsb + (160 << 10));        // 2 KB
  // xt: 16 MB. Use ws if it fits, else borrow the emb_out region of d_out
  // (k_xpose writes it, k_argmin reads it, k_out overwrites it afterwards).
  const size_t need = (192 << 10) + (size_t)NPIX * DIM * 4;
  float* xt = (ws_size >= need) ? (float*)(wsb + (192 << 10)) : (out + NPIX);

  k_xpose <<<256,  256, 0, stream>>>(x, xt);
  k_cbnorm<<<2048, 256, 0, stream>>>(cb, cbn);
  k_xnorm <<<4096, 256, 0, stream>>>(xt, xn);
  k_argmin<<<256,  512, 0, stream>>>(xt, cb, cbn, xn, ids);
  k_out   <<<256,  256, 0, stream>>>(x, cb, ids, out, partials);
  k_loss  <<<1,    256, 0, stream>>>(partials, out);
}

// Round 6
// 1328.001 us; speedup vs baseline: 1.6473x; 1.6473x over previous
//
#include <hip/hip_runtime.h>

#define NPIX 16384   // 16*32*32
#define DIM  256
#define NEMB 8192

// ---------------- K0: codebook squared norms (one wave per code) ----------------
__global__ __launch_bounds__(256) void k_cbnorm(const float* __restrict__ cb,
                                                float* __restrict__ cbn) {
  const int wid  = blockIdx.x * 4 + (threadIdx.x >> 6);   // code index 0..8191
  const int lane = threadIdx.x & 63;
  const float4 v = reinterpret_cast<const float4*>(cb)[wid * 64 + lane];
  float s = v.x * v.x + v.y * v.y + v.z * v.z + v.w * v.w;
#pragma unroll
  for (int m = 32; m >= 1; m >>= 1) s += __shfl_xor(s, m, 64);
  if (lane == 0) cbn[wid] = s;
}

// ---------------- K1: transpose x [b][c][hw] -> xt [pix][c] ----------------
__global__ __launch_bounds__(256) void k_xpose(const float* __restrict__ x,
                                               float* __restrict__ xt) {
  __shared__ float tile[64][36];
  const int t = threadIdx.x, blk = blockIdx.x;
  const int b = blk >> 4, hw0 = (blk & 15) << 6;
  const size_t xbase = ((size_t)b << 18) + hw0;
  const int hwL = t & 63, cr = t >> 6;     // read mapping
  const int pixL = t >> 2, c4 = t & 3;     // write mapping
  for (int ch = 0; ch < 8; ++ch) {
    __syncthreads();
#pragma unroll
    for (int i = 0; i < 8; ++i) {
      const int cloc = cr + 4 * i;         // 0..31
      tile[hwL][cloc] = x[xbase + ((size_t)(ch * 32 + cloc) << 10) + hwL];
    }
    __syncthreads();
    const size_t row = (size_t)(b * 1024 + hw0 + pixL) * 256 + ch * 32 + c4 * 8;
#pragma unroll
    for (int u = 0; u < 2; ++u)
      *reinterpret_cast<float4*>(&xt[row + u * 4]) =
          *reinterpret_cast<const float4*>(&tile[pixL][c4 * 8 + u * 4]);
  }
}

// ---------------- K1b: x row squared norms (one wave per pixel, from xt) ------
__global__ __launch_bounds__(256) void k_xnorm(const float* __restrict__ xt,
                                               float* __restrict__ xn) {
  const int wid  = blockIdx.x * 4 + (threadIdx.x >> 6);   // pixel 0..16383
  const int lane = threadIdx.x & 63;
  const float4 v = reinterpret_cast<const float4*>(xt)[(size_t)wid * 64 + lane];
  float s = fmaf(v.x, v.x, fmaf(v.y, v.y, fmaf(v.z, v.z, v.w * v.w)));
#pragma unroll
  for (int m = 32; m >= 1; m >>= 1) s += __shfl_xor(s, m, 64);
  if (lane == 0) xn[wid] = s;
}

// ---------------- K2: argmin over codes (fp32 VALU GEMM) ----------------
// 256 blocks x 512 threads. Block = 64 pixels x all 8192 codes.
// Wave w owns pixels {w+8i}; lane = code lane; codes k = ct*256 + lane + 64j.
// Per-thread tile: 8 pix x 4 codes (acc = 32 VGPRs). x fragments are wave-uniform
// scalar loads (SGPR, hoistable above barriers). cb tile (256 codes x 8 c) LDS
// double-buffered in the round-2 layout [buf][q][256][4] (measured 0 conflicts).
// dist replicates np f32: R( R(cbn+xn) - 2*dot_f32 ), first-index tie-break.
__global__ __launch_bounds__(512, 4) void k_argmin(const float* __restrict__ xt,
                                                   const float* __restrict__ cb,
                                                   const float* __restrict__ cbn,
                                                   const float* __restrict__ xn,
                                                   int* __restrict__ ids) {
  __shared__ float csm[2][2][256][4];   // [buf][q][code row][4 c] = 16 KB
  const int t    = threadIdx.x;
  const int lane = t & 63;
  const int w    = __builtin_amdgcn_readfirstlane(t >> 6);  // wave id, SGPR
  const int p0   = blockIdx.x * 64;
  const float* __restrict__ xw = xt + (size_t)(p0 + w) * 256;  // uniform base

  float xnr[8];
#pragma unroll
  for (int i = 0; i < 8; ++i) xnr[i] = xn[p0 + w + 8 * i];

  float bd[8];
  int   bk[8];
#pragma unroll
  for (int i = 0; i < 8; ++i) { bd[i] = 3.4e38f; bk[i] = 0; }

  float acc[8][4];

  const int krow = t >> 1, kq = t & 1;   // staging: code row, q-half

  float4 rr0, rr1;
  // stage u = (ct<<5)|cc : tile ct (256 codes), c-chunk cc (8 c's). 1024 stages.
  {
    rr0 = *reinterpret_cast<const float4*>(&cb[(size_t)krow * 256 + kq * 4]);
    *reinterpret_cast<float4*>(&csm[0][kq][krow][0]) = rr0;
    rr1 = *reinterpret_cast<const float4*>(&cb[(size_t)krow * 256 + 8 + kq * 4]);
  }
  __syncthreads();

#pragma unroll 1
  for (int u = 0; u < 1024; ++u) {
    const int buf = u & 1, ct = u >> 5, cc = u & 31;
    // write stage u+1 (loaded last iter) into the other buffer
    if (u + 1 < 1024) {
      const float4 wv = (u & 1) ? rr0 : rr1;
      *reinterpret_cast<float4*>(&csm[buf ^ 1][kq][krow][0]) = wv;
    }
    // prefetch stage u+2
    if (u + 2 < 1024) {
      const int u2 = u + 2, ct2 = u2 >> 5, cc2 = u2 & 31;
      const float4 lv = *reinterpret_cast<const float4*>(
          &cb[(size_t)(ct2 * 256 + krow) * 256 + cc2 * 8 + kq * 4]);
      if (u & 1) rr1 = lv; else rr0 = lv;
    }
    if (cc == 0) {
#pragma unroll
      for (int i = 0; i < 8; ++i)
#pragma unroll
        for (int j = 0; j < 4; ++j) acc[i][j] = 0.f;
    }
#pragma unroll
    for (int q = 0; q < 2; ++q) {
      float4 xa[8], ca[4];
#pragma unroll
      for (int i = 0; i < 8; ++i)
        xa[i] = *reinterpret_cast<const float4*>(&xw[i * 2048 + cc * 8 + q * 4]);
#pragma unroll
      for (int j = 0; j < 4; ++j)
        ca[j] = *reinterpret_cast<const float4*>(&csm[buf][q][lane + 64 * j][0]);
#pragma unroll
      for (int i = 0; i < 8; ++i)
#pragma unroll
        for (int j = 0; j < 4; ++j) {
          acc[i][j] = fmaf(xa[i].x, ca[j].x, acc[i][j]);
          acc[i][j] = fmaf(xa[i].y, ca[j].y, acc[i][j]);
          acc[i][j] = fmaf(xa[i].z, ca[j].z, acc[i][j]);
          acc[i][j] = fmaf(xa[i].w, ca[j].w, acc[i][j]);
        }
    }
    if (cc == 31) {   // epilogue for code tile ct
#pragma unroll
      for (int j = 0; j < 4; ++j) {
        const int k = ct * 256 + lane + 64 * j;
        const float cn = cbn[k];
#pragma unroll
        for (int i = 0; i < 8; ++i) {
          const float sq = cn + xnr[i];
          const float d  = fmaf(-2.f, acc[i][j], sq);
          if (d < bd[i]) { bd[i] = d; bk[i] = k; }   // ascending k -> first-min kept
        }
      }
    }
    __syncthreads();
  }

  // per-pixel lexicographic (d, k) min across the 64 lanes
#pragma unroll
  for (int i = 0; i < 8; ++i) {
    float d = bd[i];
    int   k = bk[i];
#pragma unroll
    for (int off = 32; off >= 1; off >>= 1) {
      const float d2 = __shfl_xor(d, off, 64);
      const int   k2 = __shfl_xor(k, off, 64);
      if (d2 < d || (d2 == d && k2 < k)) { d = d2; k = k2; }
    }
    if (lane == 0) ids[p0 + w + 8 * i] = k;
  }
}

// ---------------- K3: gather + emb_out + ids-as-float + loss partials ----------------
__global__ __launch_bounds__(256) void k_out(const float* __restrict__ x,
                                             const float* __restrict__ cb,
                                             const int* __restrict__ ids,
                                             float* __restrict__ out,
                                             double* __restrict__ partials) {
  __shared__ float  es[64 * 68];
  __shared__ double red[256];
  const int t = threadIdx.x, blk = blockIdx.x;
  const int n0 = blk * 64;
  const int b = blk >> 4, hw0 = (blk & 15) << 6;
  const size_t xbase = ((size_t)b << 18) + hw0;
  const int p = t >> 2, c4 = t & 3;        // staging
  const int lane = t & 63, cgr = t >> 6;   // compute
  double acc = 0.0;
  float* out_emb = out + NPIX;
  for (int cc = 0; cc < 4; ++cc) {
    const int cbase = cc * 64;
    __syncthreads();
    const int id = ids[n0 + p];
#pragma unroll
    for (int i = 0; i < 4; ++i) {
      const int cl = c4 * 16 + i * 4;
      *reinterpret_cast<float4*>(&es[p * 68 + cl]) =
          *reinterpret_cast<const float4*>(&cb[(size_t)id * 256 + cbase + cl]);
    }
    __syncthreads();
#pragma unroll
    for (int i = 0; i < 16; ++i) {
      const int c = cgr * 16 + i;
      const size_t g = xbase + ((size_t)(cbase + c) << 10) + lane;
      const float xv = x[g];
      const float ev = es[lane * 68 + c];
      const float d = xv - ev;
      acc += (double)d * (double)d;
      out_emb[g] = xv + (ev - xv);   // replicate straight-through rounding exactly
    }
  }
  if (t < 64) out[n0 + t] = (float)ids[n0 + t];
  __syncthreads();
  red[t] = acc;
  __syncthreads();
  for (int sft = 128; sft >= 1; sft >>= 1) {
    if (t < sft) red[t] += red[t + sft];
    __syncthreads();
  }
  if (t == 0) partials[blk] = red[0];
}

// ---------------- K4: finalize loss ----------------
__global__ __launch_bounds__(256) void k_loss(const double* __restrict__ partials,
                                              float* __restrict__ out) {
  __shared__ double red[256];
  const int t = threadIdx.x;
  red[t] = partials[t];
  __syncthreads();
  for (int sft = 128; sft >= 1; sft >>= 1) {
    if (t < sft) red[t] += red[t + sft];
    __syncthreads();
  }
  if (t == 0) {
    const float m = (float)(red[0] / 4194304.0);     // mean((x-emb)^2)
    out[NPIX + (size_t)NPIX * 256] = m + 0.25f * m;  // dict + BETA*commitment
  }
}

extern "C" void kernel_launch(void* const* d_in, const int* in_sizes, int n_in,
                              void* d_out, int out_size, void* d_ws, size_t ws_size,
                              hipStream_t stream) {
  const float* x  = (const float*)d_in[0];   // [16,256,32,32]
  const float* cb = (const float*)d_in[1];   // [8192,256]
  float* out = (float*)d_out;                // [ids | emb_out | loss]

  char* wsb = (char*)d_ws;
  float*  cbn      = (float*)wsb;                         // 32 KB
  float*  xn       = (float*)(wsb + (32 << 10));          // 64 KB
  int*    ids      = (int*)(wsb + (96 << 10));            // 64 KB
  double* partials = (double*)(wsb + (160 << 10));        // 2 KB
  // xt: 16 MB. Use ws if it fits, else borrow the emb_out region of d_out
  // (k_xpose writes it, k_argmin reads it, k_out overwrites it afterwards).
  const size_t need = (192 << 10) + (size_t)NPIX * DIM * 4;
  float* xt = (ws_size >= need) ? (float*)(wsb + (192 << 10)) : (out + NPIX);

  k_xpose <<<256,  256, 0, stream>>>(x, xt);
  k_cbnorm<<<2048, 256, 0, stream>>>(cb, cbn);
  k_xnorm <<<4096, 256, 0, stream>>>(xt, xn);
  k_argmin<<<256,  512, 0, stream>>>(xt, cb, cbn, xn, ids);
  k_out   <<<256,  256, 0, stream>>>(x, cb, ids, out, partials);
  k_loss  <<<1,    256, 0, stream>>>(partials, out);
}

// Round 9
// 1233.724 us; speedup vs baseline: 1.7731x; 1.0764x over previous
//
#include <hip/hip_runtime.h>

#define NPIX 16384   // 16*32*32
#define DIM  256
#define NEMB 8192

// ---------------- K0: codebook squared norms (one wave per code) ----------------
__global__ __launch_bounds__(256) void k_cbnorm(const float* __restrict__ cb,
                                                float* __restrict__ cbn) {
  const int wid  = blockIdx.x * 4 + (threadIdx.x >> 6);   // code index 0..8191
  const int lane = threadIdx.x & 63;
  const float4 v = reinterpret_cast<const float4*>(cb)[wid * 64 + lane];
  float s = v.x * v.x + v.y * v.y + v.z * v.z + v.w * v.w;
#pragma unroll
  for (int m = 32; m >= 1; m >>= 1) s += __shfl_xor(s, m, 64);
  if (lane == 0) cbn[wid] = s;
}

// ---------------- K1: transpose x [b][c][hw] -> xt [pix][c] ----------------
__global__ __launch_bounds__(256) void k_xpose(const float* __restrict__ x,
                                               float* __restrict__ xt) {
  __shared__ float tile[64][36];
  const int t = threadIdx.x, blk = blockIdx.x;
  const int b = blk >> 4, hw0 = (blk & 15) << 6;
  const size_t xbase = ((size_t)b << 18) + hw0;
  const int hwL = t & 63, cr = t >> 6;     // read mapping
  const int pixL = t >> 2, c4 = t & 3;     // write mapping
  for (int ch = 0; ch < 8; ++ch) {
    __syncthreads();
#pragma unroll
    for (int i = 0; i < 8; ++i) {
      const int cloc = cr + 4 * i;         // 0..31
      tile[hwL][cloc] = x[xbase + ((size_t)(ch * 32 + cloc) << 10) + hwL];
    }
    __syncthreads();
    const size_t row = (size_t)(b * 1024 + hw0 + pixL) * 256 + ch * 32 + c4 * 8;
#pragma unroll
    for (int u = 0; u < 2; ++u)
      *reinterpret_cast<float4*>(&xt[row + u * 4]) =
          *reinterpret_cast<const float4*>(&tile[pixL][c4 * 8 + u * 4]);
  }
}

// ---------------- K1b: x row squared norms (one wave per pixel, from xt) ------
__global__ __launch_bounds__(256) void k_xnorm(const float* __restrict__ xt,
                                               float* __restrict__ xn) {
  const int wid  = blockIdx.x * 4 + (threadIdx.x >> 6);   // pixel 0..16383
  const int lane = threadIdx.x & 63;
  const float4 v = reinterpret_cast<const float4*>(xt)[(size_t)wid * 64 + lane];
  float s = fmaf(v.x, v.x, fmaf(v.y, v.y, fmaf(v.z, v.z, v.w * v.w)));
#pragma unroll
  for (int m = 32; m >= 1; m >>= 1) s += __shfl_xor(s, m, 64);
  if (lane == 0) xn[wid] = s;
}

// ---------------- K2: argmin over codes (fp32 VALU GEMM) ----------------
// 512 blocks x 512 threads (2 blocks/CU -> blocks interleave across barriers).
// Block = 32 pixels x all 8192 codes. Wave w owns pixels {w+8i, i=0..3};
// lane = code lane; codes k = ct*256 + lane + 64j. Round-6 PASS body otherwise.
// Staging: thread t owns (sc=t&255, sq=t>>8) -> LDS byte t*16, globally linear
// (round-2 pattern, measured 0 conflicts). LDS contents per stage identical to
// round 6 -> compute reads identical -> numerics bit-identical to the PASS.
// dist replicates np f32: R( R(cbn+xn) - 2*dot_f32 ), first-index tie-break.
__global__ __launch_bounds__(512, 4) void k_argmin(const float* __restrict__ xt,
                                                   const float* __restrict__ cb,
                                                   const float* __restrict__ cbn,
                                                   const float* __restrict__ xn,
                                                   int* __restrict__ ids) {
  __shared__ float csm[2][2][256][4];   // [buf][q][code row][4 c] = 16 KB
  const int t    = threadIdx.x;
  const int lane = t & 63;
  const int w    = __builtin_amdgcn_readfirstlane(t >> 6);  // wave id, SGPR
  const int p0   = blockIdx.x * 32;
  const float* __restrict__ xw = xt + (size_t)(p0 + w) * 256;  // uniform base

  float xnr[4];
#pragma unroll
  for (int i = 0; i < 4; ++i) xnr[i] = xn[p0 + w + 8 * i];

  float bd[4];
  int   bk[4];
#pragma unroll
  for (int i = 0; i < 4; ++i) { bd[i] = 3.4e38f; bk[i] = 0; }

  float acc[4][4];

  const int sc = t & 255, sq = t >> 8;   // staging: code row, q-half (linear map)

  float4 rr0, rr1;
  // stage u = (ct<<5)|cc : tile ct (256 codes), c-chunk cc (8 c's). 1024 stages.
  {
    rr0 = *reinterpret_cast<const float4*>(&cb[(size_t)sc * 256 + sq * 4]);
    *reinterpret_cast<float4*>(&csm[0][sq][sc][0]) = rr0;
    // stage 1 is (ct=0, cc=1) -> addr = sc*256 + 8 + sq*4
    rr1 = *reinterpret_cast<const float4*>(&cb[(size_t)sc * 256 + 8 + sq * 4]);
  }
  __syncthreads();

#pragma unroll 1
  for (int u = 0; u < 1024; ++u) {
    const int buf = u & 1, ct = u >> 5, cc = u & 31;
    // write stage u+1 (loaded last iter) into the other buffer
    if (u + 1 < 1024) {
      const float4 wv = (u & 1) ? rr0 : rr1;
      *reinterpret_cast<float4*>(&csm[buf ^ 1][sq][sc][0]) = wv;
    }
    // prefetch stage u+2
    if (u + 2 < 1024) {
      const int u2 = u + 2, ct2 = u2 >> 5, cc2 = u2 & 31;
      const float4 lv = *reinterpret_cast<const float4*>(
          &cb[(size_t)(ct2 * 256 + sc) * 256 + cc2 * 8 + sq * 4]);
      if (u & 1) rr1 = lv; else rr0 = lv;
    }
    if (cc == 0) {
#pragma unroll
      for (int i = 0; i < 4; ++i)
#pragma unroll
        for (int j = 0; j < 4; ++j) acc[i][j] = 0.f;
    }
#pragma unroll
    for (int q = 0; q < 2; ++q) {
      float4 xa[4], ca[4];
#pragma unroll
      for (int i = 0; i < 4; ++i)
        xa[i] = *reinterpret_cast<const float4*>(&xw[i * 2048 + cc * 8 + q * 4]);
#pragma unroll
      for (int j = 0; j < 4; ++j)
        ca[j] = *reinterpret_cast<const float4*>(&csm[buf][q][lane + 64 * j][0]);
#pragma unroll
      for (int i = 0; i < 4; ++i)
#pragma unroll
        for (int j = 0; j < 4; ++j) {
          acc[i][j] = fmaf(xa[i].x, ca[j].x, acc[i][j]);
          acc[i][j] = fmaf(xa[i].y, ca[j].y, acc[i][j]);
          acc[i][j] = fmaf(xa[i].z, ca[j].z, acc[i][j]);
          acc[i][j] = fmaf(xa[i].w, ca[j].w, acc[i][j]);
        }
    }
    if (cc == 31) {   // epilogue for code tile ct
#pragma unroll
      for (int j = 0; j < 4; ++j) {
        const int k = ct * 256 + lane + 64 * j;
        const float cn = cbn[k];
#pragma unroll
        for (int i = 0; i < 4; ++i) {
          const float sq2 = cn + xnr[i];
          const float d   = fmaf(-2.f, acc[i][j], sq2);
          if (d < bd[i]) { bd[i] = d; bk[i] = k; }   // ascending k -> first-min kept
        }
      }
    }
    __syncthreads();
  }

  // per-pixel lexicographic (d, k) min across the 64 lanes
#pragma unroll
  for (int i = 0; i < 4; ++i) {
    float d = bd[i];
    int   k = bk[i];
#pragma unroll
    for (int off = 32; off >= 1; off >>= 1) {
      const float d2 = __shfl_xor(d, off, 64);
      const int   k2 = __shfl_xor(k, off, 64);
      if (d2 < d || (d2 == d && k2 < k)) { d = d2; k = k2; }
    }
    if (lane == 0) ids[p0 + w + 8 * i] = k;
  }
}

// ---------------- K3: gather + emb_out + ids-as-float + loss partials ----------------
__global__ __launch_bounds__(256) void k_out(const float* __restrict__ x,
                                             const float* __restrict__ cb,
                                             const int* __restrict__ ids,
                                             float* __restrict__ out,
                                             double* __restrict__ partials) {
  __shared__ float  es[64 * 68];
  __shared__ double red[256];
  const int t = threadIdx.x, blk = blockIdx.x;
  const int n0 = blk * 64;
  const int b = blk >> 4, hw0 = (blk & 15) << 6;
  const size_t xbase = ((size_t)b << 18) + hw0;
  const int p = t >> 2, c4 = t & 3;        // staging
  const int lane = t & 63, cgr = t >> 6;   // compute
  double acc = 0.0;
  float* out_emb = out + NPIX;
  for (int cc = 0; cc < 4; ++cc) {
    const int cbase = cc * 64;
    __syncthreads();
    const int id = ids[n0 + p];
#pragma unroll
    for (int i = 0; i < 4; ++i) {
      const int cl = c4 * 16 + i * 4;
      *reinterpret_cast<float4*>(&es[p * 68 + cl]) =
          *reinterpret_cast<const float4*>(&cb[(size_t)id * 256 + cbase + cl]);
    }
    __syncthreads();
#pragma unroll
    for (int i = 0; i < 16; ++i) {
      const int c = cgr * 16 + i;
      const size_t g = xbase + ((size_t)(cbase + c) << 10) + lane;
      const float xv = x[g];
      const float ev = es[lane * 68 + c];
      const float d = xv - ev;
      acc += (double)d * (double)d;
      out_emb[g] = xv + (ev - xv);   // replicate straight-through rounding exactly
    }
  }
  if (t < 64) out[n0 + t] = (float)ids[n0 + t];
  __syncthreads();
  red[t] = acc;
  __syncthreads();
  for (int sft = 128; sft >= 1; sft >>= 1) {
    if (t < sft) red[t] += red[t + sft];
    __syncthreads();
  }
  if (t == 0) partials[blk] = red[0];
}

// ---------------- K4: finalize loss ----------------
__global__ __launch_bounds__(256) void k_loss(const double* __restrict__ partials,
                                              float* __restrict__ out) {
  __shared__ double red[256];
  const int t = threadIdx.x;
  red[t] = partials[t];
  __syncthreads();
  for (int sft = 128; sft >= 1; sft >>= 1) {
    if (t < sft) red[t] += red[t + sft];
    __syncthreads();
  }
  if (t == 0) {
    const float m = (float)(red[0] / 4194304.0);     // mean((x-emb)^2)
    out[NPIX + (size_t)NPIX * 256] = m + 0.25f * m;  // dict + BETA*commitment
  }
}

extern "C" void kernel_launch(void* const* d_in, const int* in_sizes, int n_in,
                              void* d_out, int out_size, void* d_ws, size_t ws_size,
                              hipStream_t stream) {
  const float* x  = (const float*)d_in[0];   // [16,256,32,32]
  const float* cb = (const float*)d_in[1];   // [8192,256]
  float* out = (float*)d_out;                // [ids | emb_out | loss]

  char* wsb = (char*)d_ws;
  float*  cbn      = (float*)wsb;                         // 32 KB
  float*  xn       = (float*)(wsb + (32 << 10));          // 64 KB
  int*    ids      = (int*)(wsb + (96 << 10));            // 64 KB
  double* partials = (double*)(wsb + (160 << 10));        // 2 KB
  // xt: 16 MB. Use ws if it fits, else borrow the emb_out region of d_out
  // (k_xpose writes it, k_argmin reads it, k_out overwrites it afterwards).
  const size_t need = (192 << 10) + (size_t)NPIX * DIM * 4;
  float* xt = (ws_size >= need) ? (float*)(wsb + (192 << 10)) : (out + NPIX);

  k_xpose <<<256,  256, 0, stream>>>(x, xt);
  k_cbnorm<<<2048, 256, 0, stream>>>(cb, cbn);
  k_xnorm <<<4096, 256, 0, stream>>>(xt, xn);
  k_argmin<<<512,  512, 0, stream>>>(xt, cb, cbn, xn, ids);
  k_out   <<<256,  256, 0, stream>>>(x, cb, ids, out, partials);
  k_loss  <<<1,    256, 0, stream>>>(partials, out);
}

// Round 10
// 1107.610 us; speedup vs baseline: 1.9750x; 1.1139x over previous
//
#include <hip/hip_runtime.h>

#define NPIX 16384   // 16*32*32
#define DIM  256
#define NEMB 8192

// async 16B global->LDS (m97 pattern): LDS dest = wave-uniform base + lane*16
#define GLOAD16(g, l)                                                     \
  __builtin_amdgcn_global_load_lds(                                       \
      (const __attribute__((address_space(1))) void*)(g),                 \
      (__attribute__((address_space(3))) void*)(l), 16, 0, 0)

// ---------------- K0: codebook squared norms (one wave per code) ----------------
__global__ __launch_bounds__(256) void k_cbnorm(const float* __restrict__ cb,
                                                float* __restrict__ cbn) {
  const int wid  = blockIdx.x * 4 + (threadIdx.x >> 6);   // code index 0..8191
  const int lane = threadIdx.x & 63;
  const float4 v = reinterpret_cast<const float4*>(cb)[wid * 64 + lane];
  float s = v.x * v.x + v.y * v.y + v.z * v.z + v.w * v.w;
#pragma unroll
  for (int m = 32; m >= 1; m >>= 1) s += __shfl_xor(s, m, 64);
  if (lane == 0) cbn[wid] = s;
}

// ---------------- K1: transpose x [b][c][hw] -> xt [pix][c] ----------------
__global__ __launch_bounds__(256) void k_xpose(const float* __restrict__ x,
                                               float* __restrict__ xt) {
  __shared__ float tile[64][36];
  const int t = threadIdx.x, blk = blockIdx.x;
  const int b = blk >> 4, hw0 = (blk & 15) << 6;
  const size_t xbase = ((size_t)b << 18) + hw0;
  const int hwL = t & 63, cr = t >> 6;     // read mapping
  const int pixL = t >> 2, c4 = t & 3;     // write mapping
  for (int ch = 0; ch < 8; ++ch) {
    __syncthreads();
#pragma unroll
    for (int i = 0; i < 8; ++i) {
      const int cloc = cr + 4 * i;         // 0..31
      tile[hwL][cloc] = x[xbase + ((size_t)(ch * 32 + cloc) << 10) + hwL];
    }
    __syncthreads();
    const size_t row = (size_t)(b * 1024 + hw0 + pixL) * 256 + ch * 32 + c4 * 8;
#pragma unroll
    for (int u = 0; u < 2; ++u)
      *reinterpret_cast<float4*>(&xt[row + u * 4]) =
          *reinterpret_cast<const float4*>(&tile[pixL][c4 * 8 + u * 4]);
  }
}

// ---------------- K1b: x row squared norms (one wave per pixel, from xt) ------
__global__ __launch_bounds__(256) void k_xnorm(const float* __restrict__ xt,
                                               float* __restrict__ xn) {
  const int wid  = blockIdx.x * 4 + (threadIdx.x >> 6);   // pixel 0..16383
  const int lane = threadIdx.x & 63;
  const float4 v = reinterpret_cast<const float4*>(xt)[(size_t)wid * 64 + lane];
  float s = fmaf(v.x, v.x, fmaf(v.y, v.y, fmaf(v.z, v.z, v.w * v.w)));
#pragma unroll
  for (int m = 32; m >= 1; m >>= 1) s += __shfl_xor(s, m, 64);
  if (lane == 0) xn[wid] = s;
}

// ---------------- K2: argmin over codes (fp32 VALU GEMM) ----------------
// 512 blocks x 512 threads (2 blocks/CU). Block = 32 pixels x all 8192 codes.
// Wave w owns pixels {w+8i, i=0..3}; lane = code lane; codes k = ct*512+lane+64j.
// Stage = 512 codes x 16 c (csm 64 KB double-buffered), 256 stages, one barrier
// each. Staging via global_load_lds 16B: thread t -> csm[buf][q][t][0] =
// uniform base + lane*16 (linear, conflict-free); loads for stage u+1 issued at
// top of iter u, hidden under 512 FMA-instr, drained by the end-of-stage barrier.
// Numerics bit-identical to round-9 PASS: sequential ascending-c fmaf chain,
// d = R(R(cbn+xn) - 2*dot), per-thread ascending-k strict-<, lex (d,k) reduce.
__global__ __launch_bounds__(512, 4) void k_argmin(const float* __restrict__ xt,
                                                   const float* __restrict__ cb,
                                                   const float* __restrict__ cbn,
                                                   const float* __restrict__ xn,
                                                   int* __restrict__ ids) {
  __shared__ float csm[2][4][512][4];   // [buf][q][code row][4 c] = 64 KB
  const int t    = threadIdx.x;
  const int lane = t & 63;
  const int w    = __builtin_amdgcn_readfirstlane(t >> 6);  // wave id, SGPR
  const int p0   = blockIdx.x * 32;
  const float* __restrict__ xw = xt + (size_t)(p0 + w) * 256;  // uniform base

  float xnr[4];
#pragma unroll
  for (int i = 0; i < 4; ++i) xnr[i] = xn[p0 + w + 8 * i];

  float bd[4];
  int   bk[4];
#pragma unroll
  for (int i = 0; i < 4; ++i) { bd[i] = 3.4e38f; bk[i] = 0; }

  float acc[4][8];

  // prologue: stage 0 (ct=0, cc=0) -> buf0
#pragma unroll
  for (int q = 0; q < 4; ++q)
    GLOAD16(&cb[(size_t)t * 256 + q * 4], &csm[0][q][t][0]);
  __syncthreads();

#pragma unroll 1
  for (int u = 0; u < 256; ++u) {
    const int buf = u & 1, ct = u >> 4, cc = u & 15;
    // issue async loads for stage u+1 into the other buffer
    if (u + 1 < 256) {
      const int u2 = u + 1, ct2 = u2 >> 4, cc2 = u2 & 15;
      const float* src = cb + (size_t)(ct2 * 512 + t) * 256 + cc2 * 16;
#pragma unroll
      for (int q = 0; q < 4; ++q)
        GLOAD16(src + q * 4, &csm[buf ^ 1][q][t][0]);
    }
    if (cc == 0) {
#pragma unroll
      for (int i = 0; i < 4; ++i)
#pragma unroll
        for (int j = 0; j < 8; ++j) acc[i][j] = 0.f;
    }
#pragma unroll
    for (int q = 0; q < 4; ++q) {
      float4 xa[4], ca[8];
#pragma unroll
      for (int i = 0; i < 4; ++i)
        xa[i] = *reinterpret_cast<const float4*>(&xw[i * 2048 + cc * 16 + q * 4]);
#pragma unroll
      for (int j = 0; j < 8; ++j)
        ca[j] = *reinterpret_cast<const float4*>(&csm[buf][q][lane + 64 * j][0]);
#pragma unroll
      for (int i = 0; i < 4; ++i)
#pragma unroll
        for (int j = 0; j < 8; ++j) {
          acc[i][j] = fmaf(xa[i].x, ca[j].x, acc[i][j]);
          acc[i][j] = fmaf(xa[i].y, ca[j].y, acc[i][j]);
          acc[i][j] = fmaf(xa[i].z, ca[j].z, acc[i][j]);
          acc[i][j] = fmaf(xa[i].w, ca[j].w, acc[i][j]);
        }
    }
    if (cc == 15) {   // epilogue for code tile ct
#pragma unroll
      for (int j = 0; j < 8; ++j) {
        const int k = ct * 512 + lane + 64 * j;
        const float cn = cbn[k];
#pragma unroll
        for (int i = 0; i < 4; ++i) {
          const float sq2 = cn + xnr[i];
          const float d   = fmaf(-2.f, acc[i][j], sq2);
          if (d < bd[i]) { bd[i] = d; bk[i] = k; }   // ascending k -> first-min kept
        }
      }
    }
    __syncthreads();
  }

  // per-pixel lexicographic (d, k) min across the 64 lanes
#pragma unroll
  for (int i = 0; i < 4; ++i) {
    float d = bd[i];
    int   k = bk[i];
#pragma unroll
    for (int off = 32; off >= 1; off >>= 1) {
      const float d2 = __shfl_xor(d, off, 64);
      const int   k2 = __shfl_xor(k, off, 64);
      if (d2 < d || (d2 == d && k2 < k)) { d = d2; k = k2; }
    }
    if (lane == 0) ids[p0 + w + 8 * i] = k;
  }
}

// ---------------- K3: gather + emb_out + ids-as-float + loss partials ----------------
__global__ __launch_bounds__(256) void k_out(const float* __restrict__ x,
                                             const float* __restrict__ cb,
                                             const int* __restrict__ ids,
                                             float* __restrict__ out,
                                             double* __restrict__ partials) {
  __shared__ float  es[64 * 68];
  __shared__ double red[256];
  const int t = threadIdx.x, blk = blockIdx.x;
  const int n0 = blk * 64;
  const int b = blk >> 4, hw0 = (blk & 15) << 6;
  const size_t xbase = ((size_t)b << 18) + hw0;
  const int p = t >> 2, c4 = t & 3;        // staging
  const int lane = t & 63, cgr = t >> 6;   // compute
  double acc = 0.0;
  float* out_emb = out + NPIX;
  for (int cc = 0; cc < 4; ++cc) {
    const int cbase = cc * 64;
    __syncthreads();
    const int id = ids[n0 + p];
#pragma unroll
    for (int i = 0; i < 4; ++i) {
      const int cl = c4 * 16 + i * 4;
      *reinterpret_cast<float4*>(&es[p * 68 + cl]) =
          *reinterpret_cast<const float4*>(&cb[(size_t)id * 256 + cbase + cl]);
    }
    __syncthreads();
#pragma unroll
    for (int i = 0; i < 16; ++i) {
      const int c = cgr * 16 + i;
      const size_t g = xbase + ((size_t)(cbase + c) << 10) + lane;
      const float xv = x[g];
      const float ev = es[lane * 68 + c];
      const float d = xv - ev;
      acc += (double)d * (double)d;
      out_emb[g] = xv + (ev - xv);   // replicate straight-through rounding exactly
    }
  }
  if (t < 64) out[n0 + t] = (float)ids[n0 + t];
  __syncthreads();
  red[t] = acc;
  __syncthreads();
  for (int sft = 128; sft >= 1; sft >>= 1) {
    if (t < sft) red[t] += red[t + sft];
    __syncthreads();
  }
  if (t == 0) partials[blk] = red[0];
}

// ---------------- K4: finalize loss ----------------
__global__ __launch_bounds__(256) void k_loss(const double* __restrict__ partials,
                                              float* __restrict__ out) {
  __shared__ double red[256];
  const int t = threadIdx.x;
  red[t] = partials[t];
  __syncthreads();
  for (int sft = 128; sft >= 1; sft >>= 1) {
    if (t < sft) red[t] += red[t + sft];
    __syncthreads();
  }
  if (t == 0) {
    const float m = (float)(red[0] / 4194304.0);     // mean((x-emb)^2)
    out[NPIX + (size_t)NPIX * 256] = m + 0.25f * m;  // dict + BETA*commitment
  }
}

extern "C" void kernel_launch(void* const* d_in, const int* in_sizes, int n_in,
                              void* d_out, int out_size, void* d_ws, size_t ws_size,
                              hipStream_t stream) {
  const float* x  = (const float*)d_in[0];   // [16,256,32,32]
  const float* cb = (const float*)d_in[1];   // [8192,256]
  float* out = (float*)d_out;                // [ids | emb_out | loss]

  char* wsb = (char*)d_ws;
  float*  cbn      = (float*)wsb;                         // 32 KB
  float*  xn       = (float*)(wsb + (32 << 10));          // 64 KB
  int*    ids      = (int*)(wsb + (96 << 10));            // 64 KB
  double* partials = (double*)(wsb + (160 << 10));        // 2 KB
  // xt: 16 MB. Use ws if it fits, else borrow the emb_out region of d_out
  // (k_xpose writes it, k_argmin reads it, k_out overwrites it afterwards).
  const size_t need = (192 << 10) + (size_t)NPIX * DIM * 4;
  float* xt = (ws_size >= need) ? (float*)(wsb + (192 << 10)) : (out + NPIX);

  k_xpose <<<256,  256, 0, stream>>>(x, xt);
  k_cbnorm<<<2048, 256, 0, stream>>>(cb, cbn);
  k_xnorm <<<4096, 256, 0, stream>>>(xt, xn);
  k_argmin<<<512,  512, 0, stream>>>(xt, cb, cbn, xn, ids);
  k_out   <<<256,  256, 0, stream>>>(x, cb, ids, out, partials);
  k_loss  <<<1,    256, 0, stream>>>(partials, out);
}